// Round 1
// baseline (1989.510 us; speedup 1.0000x reference)
//
#include <hip/hip_runtime.h>

// LongConvBlock: out[b,l,h] = sum_{s=0}^{l} x[b,l-s,h]*kst[h,s] + x[b,l,h]*D[h]
//   kst = soft-threshold(kernel) = sign(k)*relu(|k|-0.1)
// Shapes: x [B,L,H] f32, kernel [C=1,H,L] f32, D [C=1,H] f32, out [B,L,C*H] f32.
//
// Round 0: correct fp32 register-blocked direct convolution.
//  - thread = (b, h, l-tile of TL); h across 256 threads -> coalesced x/out.
//  - s-chunks of U=8: k row loads (soft-threshold inline), rolling x window
//    in registers (zero-filled for negative indices = causal edge).
//  - heavy l-tiles dispatched first (blockIdx.x reversed) for load balance.

constexpr int B_  = 4;
constexpr int L_  = 4096;
constexpr int H_  = 1024;
constexpr int TL  = 32;            // l outputs per thread
constexpr int U   = 8;             // s-chunk size
constexpr int W   = TL + U - 1;    // rolling window = 39
constexpr int HT  = 256;           // threads per block (h span)

__global__ __launch_bounds__(HT)
void longconv_kernel(const float* __restrict__ x,
                     const float* __restrict__ k,
                     const float* __restrict__ Dskip,
                     float* __restrict__ out)
{
    const int h  = blockIdx.y * HT + threadIdx.x;     // 0..H-1
    const int b  = blockIdx.z;                         // 0..B-1
    const int lt = (int)gridDim.x - 1 - (int)blockIdx.x; // heavy tiles first
    const int L0 = lt * TL;

    const float* __restrict__ xb = x + ((size_t)b * L_) * H_ + h; // xb[m*H_] = x[b,m,h]
    const float* __restrict__ kh = k + (size_t)h * L_;            // kh[s]    = kernel[0,h,s]

    float acc[TL];
    float win[W];   // win[i] = x[b, L0 - c*U - (U-1) + i, h] for current chunk c

    // ---- init window for chunk c=0: indices L0-(U-1) .. L0+TL-1
    #pragma unroll
    for (int i = 0; i < W; ++i) {
        const int idx = L0 - (U - 1) + i;
        win[i] = (idx >= 0) ? xb[(size_t)idx * H_] : 0.0f;
    }

    // ---- skip term: acc[j] = x[b, L0+j, h] * D[h]   (win[j+U-1] == x[L0+j])
    const float Dv = Dskip[h];
    #pragma unroll
    for (int j = 0; j < TL; ++j) acc[j] = win[j + U - 1] * Dv;

    // ---- main loop over s-chunks: s in [c*U, c*U+U)
    const int cmax = L0 / U + (TL / U) - 1;   // covers s up to L0+TL-1
    for (int c = 0; c <= cmax; ++c) {
        // load + soft-threshold k row segment (per-thread row; L2/L3 cached)
        float kr[U];
        #pragma unroll
        for (int u = 0; u < U; ++u) {
            const float a = kh[c * U + u];
            const float t = fmaxf(fabsf(a) - 0.1f, 0.0f);
            kr[u] = copysignf(t, a);
        }
        // acc[j] += kr[u] * x[L0+j - (c*U+u)]  ;  x[...] = win[j + (U-1) - u]
        #pragma unroll
        for (int u = 0; u < U; ++u) {
            #pragma unroll
            for (int j = 0; j < TL; ++j) {
                acc[j] = fmaf(kr[u], win[j + (U - 1) - u], acc[j]);
            }
        }
        // slide window down by U for next chunk
        if (c < cmax) {
            #pragma unroll
            for (int i = W - 1; i >= U; --i) win[i] = win[i - U];
            #pragma unroll
            for (int i = 0; i < U; ++i) {
                const int idx = L0 - (c + 1) * U - (U - 1) + i;
                win[i] = (idx >= 0) ? xb[(size_t)idx * H_] : 0.0f;
            }
        }
    }

    // ---- store: out[b, L0+j, h]
    float* __restrict__ ob = out + ((size_t)b * L_ + L0) * H_ + h;
    #pragma unroll
    for (int j = 0; j < TL; ++j) ob[(size_t)j * H_] = acc[j];
}

extern "C" void kernel_launch(void* const* d_in, const int* in_sizes, int n_in,
                              void* d_out, int out_size, void* d_ws, size_t ws_size,
                              hipStream_t stream)
{
    const float* x  = (const float*)d_in[0];  // [B, L, H]
    const float* k  = (const float*)d_in[1];  // [1, H, L]
    const float* Dk = (const float*)d_in[2];  // [1, H]
    float* out = (float*)d_out;               // [B, L, H]

    dim3 grid(L_ / TL, H_ / HT, B_);          // (128, 4, 4)
    dim3 block(HT);
    longconv_kernel<<<grid, block, 0, stream>>>(x, k, Dk, out);
}

// Round 2
// 808.447 us; speedup vs baseline: 2.4609x; 2.4609x over previous
//
#include <hip/hip_runtime.h>

// LongConvBlock via block-Toeplitz MFMA (bf16 32x32x16), fp32 accumulate.
// out[b,l,h] = sum_j x[b,j,h] * k'[h, l-j],  k'[0] += D[h] (skip folded in).
//
// Per wave: one h, one 256-output supertile [Ls, Ls+256).
//   D[m=i][n=(t,b)] : i in [0,32) row-in-tile, t in [0,8) 32-tiles, b in [0,4)
//   chunk ch: j0 = -224 + 16*ch;  c = Ls - j0
//   A[i][kk] = k'[c + i - kk]   (Toeplitz band; kk = 8q + j, q = lane>>5)
//   B[kk][(t,b)] = x[b, j0 + 32t + kk, h]
// Zero-padding (causality + edges) baked into the staged data:
//   xT[b][h][i] = (i >= PADX) ? bf16(x[b, i-PADX, h]) : 0        (PADX=256)
//   kR[p][h][i] = (i+p <= L-1) ? bf16(k'[h, L-1-i-p]) : 0        (p = parity copy)
// Reversal makes each lane's 8 A-taps contiguous-ascending; parity copies give
// 4B alignment (lane shift -m breaks 16B alignment).

typedef __attribute__((ext_vector_type(8)))  short s16x8;   // 8 bf16 (4 VGPRs)
typedef __attribute__((ext_vector_type(16))) float f32x16;  // 32x32 acc

constexpr int B_ = 4, L_ = 4096, H_ = 1024;
constexpr int PADX = 256;
constexpr int LX = L_ + PADX;   // 4352, xT row length
constexpr int LK = L_ + 32;     // 4128, kR row length (tail zeros)
constexpr int ST = 256;         // supertile outputs per wave
constexpr int NST = L_ / ST;    // 16

constexpr size_t XT_ELEMS = (size_t)B_ * H_ * LX;
constexpr size_t KR_ELEMS = (size_t)2 * H_ * LK;
constexpr size_t WS_NEEDED = (XT_ELEMS + KR_ELEMS) * sizeof(unsigned short);

__device__ __forceinline__ unsigned short f2bf(float f) {
    unsigned int u = __builtin_bit_cast(unsigned int, f);
    u += 0x7fffu + ((u >> 16) & 1u);            // round-to-nearest-even
    return (unsigned short)(u >> 16);
}

// ---- prep: x [B,L,H] f32 -> xT [B][H][PADX+L] bf16 (LDS tile transpose) ----
__global__ __launch_bounds__(256)
void prep_x(const float* __restrict__ x, unsigned short* __restrict__ xT)
{
    __shared__ float tile[64][65];              // +1 pad: conflict-free columns
    const int nHt = H_ / 64;                    // 16
    const int nLt = L_ / 64;                    // 64
    const int bid = blockIdx.x;
    const int b  = bid / (nLt * nHt);
    const int r  = bid % (nLt * nHt);
    const int l0 = (r / nHt) * 64;
    const int h0 = (r % nHt) * 64;
    const int w  = threadIdx.x >> 6;
    const int ln = threadIdx.x & 63;

    #pragma unroll
    for (int rr = 0; rr < 16; ++rr) {
        const int lr = w * 16 + rr;
        tile[lr][ln] = x[((size_t)b * L_ + l0 + lr) * H_ + h0 + ln]; // coalesced
    }
    __syncthreads();
    #pragma unroll
    for (int rr = 0; rr < 16; ++rr) {
        const int hh = w * 16 + rr;
        xT[((size_t)b * H_ + h0 + hh) * LX + PADX + l0 + ln] = f2bf(tile[ln][hh]);
    }
}

// ---- prep: kernel [1,H,L] f32 -> kR [2][H][LK] bf16 reversed, D folded ----
__global__ __launch_bounds__(256)
void prep_k(const float* __restrict__ kin, const float* __restrict__ Dk,
            unsigned short* __restrict__ kR)
{
    const int h = blockIdx.x;
    const float Dv = Dk[h];
    for (int l = threadIdx.x; l < L_; l += 256) {
        const float a = kin[(size_t)h * L_ + l];
        float v = copysignf(fmaxf(fabsf(a) - 0.1f, 0.0f), a);
        if (l == 0) v += Dv;                    // fold skip term into tap 0
        const unsigned short bv = f2bf(v);
        kR[(size_t)h * LK + (L_ - 1 - l)] = bv;                   // copy p=0
        if (l <= L_ - 2)
            kR[((size_t)H_ + h) * LK + (L_ - 2 - l)] = bv;        // copy p=1
    }
}

// ---- main: one wave = one h, one 256-l supertile, all 4 b ----
__global__ __launch_bounds__(256)
void longconv_mfma(const unsigned short* __restrict__ xT,
                   const unsigned short* __restrict__ kR,
                   float* __restrict__ out)
{
    const int w  = threadIdx.x >> 6;
    const int ln = threadIdx.x & 63;
    const int gw = blockIdx.x * 4 + w;
    const int h   = gw >> 4;                    // block's 4 waves share h (L2)
    const int sti = gw & 15;
    const int Ls  = (NST - 1 - sti) * ST;       // big supertiles dispatch first
    const int NCH = Ls / 16 + 16;               // multiple of 16

    const int m = ln & 31;                      // A-row i / B-col n
    const int q = ln >> 5;                      // k-octet select

    // A pointer: frag[j] = kR[p][h][(base0-p) + 16*ch + j] = k'[c + m - 8q - j]
    const int base0 = (L_ - 225) - Ls - m + 8 * q;
    const int p = base0 & 1;
    const unsigned int* aptr =
        (const unsigned int*)(kR + ((size_t)p * H_ + h) * LK + (base0 - p));

    // B pointer: frag[j] = x[b, j0 + 32t + 8q + j, h]  (16B aligned)
    const int t = m >> 2, b = m & 3;
    const unsigned short* bptr =
        xT + ((size_t)b * H_ + h) * LX + (32 + 32 * t + 8 * q);

    f32x16 acc = {};
    #pragma unroll 4
    for (int ch = 0; ch < NCH; ++ch) {
        s16x8 af;
        __builtin_memcpy(&af, aptr + 8 * (size_t)ch, 16);  // 4B-aligned 16B
        const s16x8 bfr = *(const s16x8*)(bptr + 16 * (size_t)ch);
        acc = __builtin_amdgcn_mfma_f32_32x32x16_bf16(af, bfr, acc, 0, 0, 0);
    }

    // D layout (m74/m101): col = lane&31 = n, row = (r&3) + 8*(r>>2) + 4*(lane>>5)
    #pragma unroll
    for (int r = 0; r < 16; ++r) {
        const int row = (r & 3) + 8 * (r >> 2) + 4 * q;
        const int l = Ls + 32 * t + row;
        out[((size_t)b * L_ + l) * H_ + h] = acc[r];   // L2 write-combines per-16h lines
    }
}

// ---- fallback: round-1 fp32 kernel (used only if ws_size too small) ----
constexpr int TLf = 32, Uf = 8, Wf = TLf + Uf - 1, HTf = 256;

__global__ __launch_bounds__(HTf)
void longconv_fp32(const float* __restrict__ x, const float* __restrict__ k,
                   const float* __restrict__ Dskip, float* __restrict__ out)
{
    const int h  = blockIdx.y * HTf + threadIdx.x;
    const int b  = blockIdx.z;
    const int lt = (int)gridDim.x - 1 - (int)blockIdx.x;
    const int L0 = lt * TLf;
    const float* __restrict__ xb = x + ((size_t)b * L_) * H_ + h;
    const float* __restrict__ kh = k + (size_t)h * L_;
    float acc[TLf]; float win[Wf];
    #pragma unroll
    for (int i = 0; i < Wf; ++i) {
        const int idx = L0 - (Uf - 1) + i;
        win[i] = (idx >= 0) ? xb[(size_t)idx * H_] : 0.0f;
    }
    const float Dv = Dskip[h];
    #pragma unroll
    for (int j = 0; j < TLf; ++j) acc[j] = win[j + Uf - 1] * Dv;
    const int cmax = L0 / Uf + (TLf / Uf) - 1;
    for (int c = 0; c <= cmax; ++c) {
        float kr[Uf];
        #pragma unroll
        for (int u = 0; u < Uf; ++u) {
            const float a = kh[c * Uf + u];
            kr[u] = copysignf(fmaxf(fabsf(a) - 0.1f, 0.0f), a);
        }
        #pragma unroll
        for (int u = 0; u < Uf; ++u)
            #pragma unroll
            for (int j = 0; j < TLf; ++j)
                acc[j] = fmaf(kr[u], win[j + (Uf - 1) - u], acc[j]);
        if (c < cmax) {
            #pragma unroll
            for (int i = Wf - 1; i >= Uf; --i) win[i] = win[i - Uf];
            #pragma unroll
            for (int i = 0; i < Uf; ++i) {
                const int idx = L0 - (c + 1) * Uf - (Uf - 1) + i;
                win[i] = (idx >= 0) ? xb[(size_t)idx * H_] : 0.0f;
            }
        }
    }
    float* __restrict__ ob = out + ((size_t)b * L_ + L0) * H_ + h;
    #pragma unroll
    for (int j = 0; j < TLf; ++j) ob[(size_t)j * H_] = acc[j];
}

extern "C" void kernel_launch(void* const* d_in, const int* in_sizes, int n_in,
                              void* d_out, int out_size, void* d_ws, size_t ws_size,
                              hipStream_t stream)
{
    const float* x  = (const float*)d_in[0];   // [B, L, H]
    const float* k  = (const float*)d_in[1];   // [1, H, L]
    const float* Dk = (const float*)d_in[2];   // [1, H]
    float* out = (float*)d_out;                // [B, L, H]

    if (ws_size >= WS_NEEDED) {
        unsigned short* xT = (unsigned short*)d_ws;
        unsigned short* kR = xT + XT_ELEMS;
        hipMemsetAsync(d_ws, 0, WS_NEEDED, stream);     // pads/causal zeros
        prep_x<<<dim3(B_ * (L_ / 64) * (H_ / 64)), dim3(256), 0, stream>>>(x, xT);
        prep_k<<<dim3(H_), dim3(256), 0, stream>>>(k, Dk, kR);
        longconv_mfma<<<dim3((H_ * NST) / 4), dim3(256), 0, stream>>>(xT, kR, out);
    } else {
        dim3 grid(L_ / TLf, H_ / HTf, B_);
        longconv_fp32<<<grid, dim3(HTf), 0, stream>>>(x, k, Dk, out);
    }
}

// Round 3
// 242.755 us; speedup vs baseline: 8.1955x; 3.3303x over previous
//
#include <hip/hip_runtime.h>

// LongConvBlock, round 3: block-Toeplitz MFMA with LDS-staged fragments.
// out[b,l,h] = sum_j x[b,j,h] * k'[h,l-j],  k'[0] += D[h].
//
// Main kernel: block = one h (grid 1024), 4 waves. Stage full x window
// (4 b rows) + reversed-k band (2 parity copies) into LDS once; then a
// barrier-free MFMA loop (wave w owns si {w,7-w,8+w,15-w}: equal work).
// Per chunk: A = 4x ds_read_b32 (4B-aligned via parity copy), B = ds_read_b128
// (16B-aligned, b-XOR swizzle breaks bank conflicts), 1 MFMA 32x32x16 bf16.
// Output staged through per-wave LDS area (t-rotation vs bank conflicts) ->
// coalesced packed-bf16 stores to out_tmp[b][h][l]; separate kernel
// transposes to out[b][l][h] fp32.

typedef __attribute__((ext_vector_type(8)))  short s16x8;   // 8 bf16
typedef __attribute__((ext_vector_type(16))) float f32x16;  // 32x32 acc
typedef __attribute__((ext_vector_type(4)))  float f32x4;
typedef __attribute__((ext_vector_type(4)))  unsigned int u32x4;

constexpr int B_ = 4, L_ = 4096, H_ = 1024;
constexpr int PADX = 256;
constexpr int LX = L_ + PADX;    // 4352 xT row
constexpr int LK = L_ + 32;      // 4128 kR row
constexpr int ST = 256;          // outputs per (wave, si)
constexpr int NST = L_ / ST;     // 16

constexpr size_t XT_ELEMS = (size_t)B_ * H_ * LX;
constexpr size_t KR_ELEMS = (size_t)2 * H_ * LK;
constexpr size_t OT_ELEMS = (size_t)B_ * H_ * L_;           // out_tmp bf16 [B][H][L]
constexpr size_t WS_NEEDED = (XT_ELEMS + KR_ELEMS + OT_ELEMS) * sizeof(unsigned short);

// LDS layout (main kernel)
constexpr int XS_ROW  = 4320;            // x window elements per b: l in [-224, 4095]
constexpr int XS_BLKS = XS_ROW / 8;      // 540 16B-blocks per row
constexpr int XS_US   = B_ * XS_ROW;     // 17280 ushorts
constexpr int KS_US   = 2 * LK;          // 8256 ushorts (2 parity copies)
constexpr int OAREA_DW = 4 * 132;        // 528 dwords per wave (4 b x 128 + pad)
constexpr int SMEM_BYTES = XS_US * 2 + KS_US * 2 + 4 * OAREA_DW * 4;  // 59520 <= 64K

__device__ __forceinline__ unsigned short f2bf(float f) {
    unsigned int u = __builtin_bit_cast(unsigned int, f);
    u += 0x7fffu + ((u >> 16) & 1u);     // RTNE
    return (unsigned short)(u >> 16);
}

// ---- prep: x [B,L,H] f32 -> xT [B][H][PADX+L] bf16 (LDS tile transpose) ----
__global__ __launch_bounds__(256)
void prep_x(const float* __restrict__ x, unsigned short* __restrict__ xT)
{
    __shared__ float tile[64][65];
    const int nHt = H_ / 64, nLt = L_ / 64;
    const int bid = blockIdx.x;
    const int b  = bid / (nLt * nHt);
    const int r  = bid % (nLt * nHt);
    const int l0 = (r / nHt) * 64;
    const int h0 = (r % nHt) * 64;
    const int w  = threadIdx.x >> 6;
    const int ln = threadIdx.x & 63;
    #pragma unroll
    for (int rr = 0; rr < 16; ++rr) {
        const int lr = w * 16 + rr;
        tile[lr][ln] = x[((size_t)b * L_ + l0 + lr) * H_ + h0 + ln];
    }
    __syncthreads();
    #pragma unroll
    for (int rr = 0; rr < 16; ++rr) {
        const int hh = w * 16 + rr;
        xT[((size_t)b * H_ + h0 + hh) * LX + PADX + l0 + ln] = f2bf(tile[ln][hh]);
    }
}

// ---- prep: kernel [1,H,L] f32 -> kR [2][H][LK] bf16 reversed, D folded ----
__global__ __launch_bounds__(256)
void prep_k(const float* __restrict__ kin, const float* __restrict__ Dk,
            unsigned short* __restrict__ kR)
{
    const int h = blockIdx.x;
    const float Dv = Dk[h];
    for (int l = threadIdx.x; l < L_; l += 256) {
        const float a = kin[(size_t)h * L_ + l];
        float v = copysignf(fmaxf(fabsf(a) - 0.1f, 0.0f), a);
        if (l == 0) v += Dv;
        const unsigned short bv = f2bf(v);
        kR[(size_t)h * LK + (L_ - 1 - l)] = bv;                   // parity 0
        if (l <= L_ - 2)
            kR[((size_t)H_ + h) * LK + (L_ - 2 - l)] = bv;        // parity 1
    }
}

// ---- main ----
__global__ __launch_bounds__(256)
void longconv_main(const unsigned short* __restrict__ xT,
                   const unsigned short* __restrict__ kR,
                   unsigned int* __restrict__ outT)    // out_tmp as packed bf16 pairs
{
    __shared__ __align__(16) unsigned char smem[SMEM_BYTES];
    unsigned short* xs = (unsigned short*)smem;
    unsigned short* ks = (unsigned short*)(smem + (size_t)XS_US * 2);
    float* oarea = (float*)(smem + (size_t)XS_US * 2 + (size_t)KS_US * 2);

    const int h   = blockIdx.x;
    const int tid = threadIdx.x;

    // ---- stage in: x window (b-XOR swizzled 16B blocks) + k band (2 copies)
    constexpr int NXU = XS_BLKS * 4;          // 2160
    constexpr int NKU = 2 * (LK / 8);         // 1032
    for (int u = tid; u < NXU + NKU; u += 256) {
        if (u < NXU) {
            const int b = u / XS_BLKS, n = u - b * XS_BLKS;
            const u32x4 v = *(const u32x4*)(xT + ((size_t)b * H_ + h) * LX + 32 + n * 8);
            *(u32x4*)(xs + (size_t)b * XS_ROW + (size_t)(n ^ b) * 8) = v;
        } else {
            const int v2 = u - NXU;
            const int p = v2 / (LK / 8), i = v2 - p * (LK / 8);
            const u32x4 v = *(const u32x4*)(kR + ((size_t)p * H_ + h) * LK + i * 8);
            *(u32x4*)(ks + (size_t)p * LK + (size_t)i * 8) = v;
        }
    }
    __syncthreads();

    const int w  = tid >> 6, ln = tid & 63;
    const int m  = ln & 31,  q  = ln >> 5;
    const int t  = m >> 2,   b  = m & 3;
    const int sis[4] = { w, 7 - w, 8 + w, 15 - w };   // equal total work per wave

    for (int ph = 0; ph < 4; ++ph) {
        const int si  = sis[ph];
        const int Ls  = si * ST;
        const int NCH = 16 * si + 16;
        // A: frag[j] = k'[c+m-8q-j] = kR[p][(a0-p) + 16ch + j],  a0 = 3871-Ls-m+8q
        const int a0 = 3871 - Ls - m + 8 * q;
        const int p  = a0 & 1;
        const unsigned int* ap = (const unsigned int*)(ks + p * LK + (a0 - p));
        const unsigned short* xrow = xs + (size_t)b * XS_ROW;
        const int nb = 4 * t + q;                 // B block index n = 2ch + nb

        f32x16 acc = {};
        #pragma unroll 2
        for (int ch = 0; ch < NCH; ++ch) {
            u32x4 aw;
            aw.x = ap[8 * ch + 0]; aw.y = ap[8 * ch + 1];
            aw.z = ap[8 * ch + 2]; aw.w = ap[8 * ch + 3];
            const s16x8 af = __builtin_bit_cast(s16x8, aw);
            const int n = 2 * ch + nb;
            const s16x8 bfr = *(const s16x8*)(xrow + (size_t)(n ^ b) * 8);
            acc = __builtin_amdgcn_mfma_f32_32x32x16_bf16(af, bfr, acc, 0, 0, 0);
        }

        // ---- stage out: per-wave LDS area, two half-tiles (rows 0-15, 16-31)
        float* ar = oarea + w * OAREA_DW;
        #pragma unroll
        for (int rh = 0; rh < 2; ++rh) {
            #pragma unroll
            for (int rr2 = 0; rr2 < 2; ++rr2) {
                // acc regs r = 4*(2rh+rr2)+j -> row = 16rh + 8rr2 + 4q + j
                const int base4 = (8 * rr2 + 4 * q + 4 * t) & 15;  // t-rotation
                f32x4 qd;
                qd.x = acc[4 * (2 * rh + rr2) + 0];
                qd.y = acc[4 * (2 * rh + rr2) + 1];
                qd.z = acc[4 * (2 * rh + rr2) + 2];
                qd.w = acc[4 * (2 * rh + rr2) + 3];
                *(f32x4*)(ar + b * 132 + 16 * t + base4) = qd;
            }
            __asm__ volatile("s_waitcnt lgkmcnt(0)" ::: "memory");  // wave-local W->R
            #pragma unroll
            for (int bb = 0; bb < 4; ++bb) {
                const int g  = ln >> 3;            // tile-col t of this lane's pair
                const int uu = (2 * ln) & 15;      // row-within-16 (even)
                const int s  = (uu + 4 * g) & 15;  // un-rotate
                const float v0 = ar[bb * 132 + 16 * g + s];
                const float v1 = ar[bb * 132 + 16 * g + s + 1];
                const int l = 32 * g + 16 * rh + uu;
                const unsigned int pk =
                    (unsigned int)f2bf(v0) | ((unsigned int)f2bf(v1) << 16);
                outT[(((size_t)bb * H_ + h) * L_ + Ls + l) >> 1] = pk;
            }
            __asm__ volatile("s_waitcnt lgkmcnt(0)" ::: "memory");  // R before next W
        }
    }
}

// ---- out_tmp bf16 [B][H][L] -> out f32 [B][L][H] ----
__global__ __launch_bounds__(256)
void untranspose(const unsigned short* __restrict__ outT, float* __restrict__ out)
{
    __shared__ float tile[64][65];
    const int nHt = H_ / 64, nLt = L_ / 64;
    const int bid = blockIdx.x;
    const int b  = bid / (nLt * nHt);
    const int r  = bid % (nLt * nHt);
    const int l0 = (r / nHt) * 64;
    const int h0 = (r % nHt) * 64;
    const int w  = threadIdx.x >> 6;
    const int ln = threadIdx.x & 63;
    #pragma unroll
    for (int rr = 0; rr < 16; ++rr) {
        const int hh = w * 16 + rr;
        const unsigned int fu =
            ((unsigned int)outT[((size_t)b * H_ + h0 + hh) * L_ + l0 + ln]) << 16;
        tile[hh][ln] = __builtin_bit_cast(float, fu);
    }
    __syncthreads();
    #pragma unroll
    for (int rr = 0; rr < 16; ++rr) {
        const int ll = w * 16 + rr;
        out[((size_t)b * L_ + l0 + ll) * H_ + h0 + ln] = tile[ln][ll];
    }
}

// ---- fallback: round-1 fp32 kernel (only if ws too small) ----
constexpr int TLf = 32, Uf = 8, Wf = TLf + Uf - 1, HTf = 256;

__global__ __launch_bounds__(HTf)
void longconv_fp32(const float* __restrict__ x, const float* __restrict__ k,
                   const float* __restrict__ Dskip, float* __restrict__ out)
{
    const int h  = blockIdx.y * HTf + threadIdx.x;
    const int b  = blockIdx.z;
    const int lt = (int)gridDim.x - 1 - (int)blockIdx.x;
    const int L0 = lt * TLf;
    const float* __restrict__ xb = x + ((size_t)b * L_) * H_ + h;
    const float* __restrict__ kh = k + (size_t)h * L_;
    float acc[TLf]; float win[Wf];
    #pragma unroll
    for (int i = 0; i < Wf; ++i) {
        const int idx = L0 - (Uf - 1) + i;
        win[i] = (idx >= 0) ? xb[(size_t)idx * H_] : 0.0f;
    }
    const float Dv = Dskip[h];
    #pragma unroll
    for (int j = 0; j < TLf; ++j) acc[j] = win[j + Uf - 1] * Dv;
    const int cmax = L0 / Uf + (TLf / Uf) - 1;
    for (int c = 0; c <= cmax; ++c) {
        float kr[Uf];
        #pragma unroll
        for (int u = 0; u < Uf; ++u) {
            const float a = kh[c * Uf + u];
            kr[u] = copysignf(fmaxf(fabsf(a) - 0.1f, 0.0f), a);
        }
        #pragma unroll
        for (int u = 0; u < Uf; ++u)
            #pragma unroll
            for (int j = 0; j < TLf; ++j)
                acc[j] = fmaf(kr[u], win[j + (Uf - 1) - u], acc[j]);
        if (c < cmax) {
            #pragma unroll
            for (int i = Wf - 1; i >= Uf; --i) win[i] = win[i - Uf];
            #pragma unroll
            for (int i = 0; i < Uf; ++i) {
                const int idx = L0 - (c + 1) * Uf - (Uf - 1) + i;
                win[i] = (idx >= 0) ? xb[(size_t)idx * H_] : 0.0f;
            }
        }
    }
    float* __restrict__ ob = out + ((size_t)b * L_ + L0) * H_ + h;
    #pragma unroll
    for (int j = 0; j < TLf; ++j) ob[(size_t)j * H_] = acc[j];
}

extern "C" void kernel_launch(void* const* d_in, const int* in_sizes, int n_in,
                              void* d_out, int out_size, void* d_ws, size_t ws_size,
                              hipStream_t stream)
{
    const float* x  = (const float*)d_in[0];   // [B, L, H]
    const float* k  = (const float*)d_in[1];   // [1, H, L]
    const float* Dk = (const float*)d_in[2];   // [1, H]
    float* out = (float*)d_out;                // [B, L, H]

    if (ws_size >= WS_NEEDED) {
        unsigned short* xT = (unsigned short*)d_ws;
        unsigned short* kR = xT + XT_ELEMS;
        unsigned short* oT = kR + KR_ELEMS;
        hipMemsetAsync(d_ws, 0, (XT_ELEMS + KR_ELEMS) * sizeof(unsigned short), stream);
        prep_x<<<dim3(B_ * (L_ / 64) * (H_ / 64)), dim3(256), 0, stream>>>(x, xT);
        prep_k<<<dim3(H_), dim3(256), 0, stream>>>(k, Dk, kR);
        longconv_main<<<dim3(H_), dim3(256), 0, stream>>>(xT, kR, (unsigned int*)oT);
        untranspose<<<dim3(B_ * (L_ / 64) * (H_ / 64)), dim3(256), 0, stream>>>(oT, out);
    } else {
        dim3 grid(L_ / TLf, H_ / HTf, B_);
        longconv_fp32<<<grid, dim3(HTf), 0, stream>>>(x, k, Dk, out);
    }
}

// Round 4
// 239.489 us; speedup vs baseline: 8.3073x; 1.0136x over previous
//
#include <hip/hip_runtime.h>

// LongConvBlock, round 4: block-Toeplitz MFMA, LDS-staged, A-stationary K-loop.
// out[b,l,h] = sum_j x[b,j,h] * k'[h,l-j],  k'[0] += D[h].
//
// Main: block = one h (grid 1024), 4 waves, wave w owns si {w,7-w,8+w,15-w}
// with 4 accumulators. Loop r = 16ch-256si (A-fragment position) descending:
// load A once (2x ds_read2_b32 via parity copies), up to 4x (ds_read_b128 B +
// MFMA). si active iff -256si <= r <= 240 -> 4 sub-loops, no per-iter branch.
// Pipeline: 3 dispatches (prep fused, writes own pads; main; untranspose),
// 16B/lane global access everywhere.

typedef __attribute__((ext_vector_type(8)))  short s16x8;   // 8 bf16
typedef __attribute__((ext_vector_type(16))) float f32x16;  // 32x32 acc
typedef __attribute__((ext_vector_type(4)))  float f32x4;
typedef __attribute__((ext_vector_type(4)))  unsigned int u32x4;

constexpr int B_ = 4, L_ = 4096, H_ = 1024;
constexpr int PADX = 256;
constexpr int LX = L_ + PADX;    // 4352 xT row
constexpr int LK = L_ + 32;      // 4128 kR row
constexpr int ST = 256;          // outputs per (wave, si)
constexpr int NST = L_ / ST;     // 16

constexpr size_t XT_ELEMS = (size_t)B_ * H_ * LX;
constexpr size_t KR_ELEMS = (size_t)2 * H_ * LK;
constexpr size_t OT_ELEMS = (size_t)B_ * H_ * L_;
constexpr size_t WS_NEEDED = (XT_ELEMS + KR_ELEMS + OT_ELEMS) * sizeof(unsigned short);

constexpr int XS_ROW  = 4320;           // x window per b (l in [-224,4095])
constexpr int XS_BLKS = XS_ROW / 8;     // 540
constexpr int XS_US   = B_ * XS_ROW;    // 17280
constexpr int KS_US   = 2 * LK;         // 8256
constexpr int OAREA_DW = 4 * 132;       // 528 dwords per wave
constexpr int SMEM_BYTES = XS_US * 2 + KS_US * 2 + 4 * OAREA_DW * 4;  // 59520

constexpr int nHt = H_ / 64, nLt = L_ / 64;
constexpr int NXB = B_ * nLt * nHt;     // 4096 x-tile blocks in prep

__device__ __forceinline__ unsigned short f2bf(float f) {
    unsigned int u = __builtin_bit_cast(unsigned int, f);
    u += 0x7fffu + ((u >> 16) & 1u);    // RTNE
    return (unsigned short)(u >> 16);
}
__device__ __forceinline__ float bf2f(unsigned short u) {
    return __builtin_bit_cast(float, (unsigned int)u << 16);
}

// ---- prep (fused): x -> xT bf16 transposed (+left pad), k -> kR reversed ----
__global__ __launch_bounds__(256)
void prep(const float* __restrict__ x, const float* __restrict__ kin,
          const float* __restrict__ Dk,
          unsigned short* __restrict__ xT, unsigned short* __restrict__ kR)
{
    const int bid = blockIdx.x;
    if (bid < NXB) {
        __shared__ float tile[64][65];
        const int b  = bid / (nLt * nHt);
        const int r0 = bid % (nLt * nHt);
        const int l0 = (r0 / nHt) * 64;
        const int h0 = (r0 % nHt) * 64;
        const int w  = threadIdx.x >> 6;
        const int ln = threadIdx.x & 63;
        #pragma unroll
        for (int rr = 0; rr < 16; ++rr) {
            const int lr = w * 16 + rr;
            tile[lr][ln] = x[((size_t)b * L_ + l0 + lr) * H_ + h0 + ln];
        }
        __syncthreads();
        const int j  = threadIdx.x;
        const int lg = j & 7;                 // 8-element l group
        #pragma unroll
        for (int pp = 0; pp < 2; ++pp) {
            const int hh = (j >> 3) + 32 * pp;
            unsigned int w0 = (unsigned int)f2bf(tile[8*lg+0][hh]) | ((unsigned int)f2bf(tile[8*lg+1][hh]) << 16);
            unsigned int w1 = (unsigned int)f2bf(tile[8*lg+2][hh]) | ((unsigned int)f2bf(tile[8*lg+3][hh]) << 16);
            unsigned int w2 = (unsigned int)f2bf(tile[8*lg+4][hh]) | ((unsigned int)f2bf(tile[8*lg+5][hh]) << 16);
            unsigned int w3 = (unsigned int)f2bf(tile[8*lg+6][hh]) | ((unsigned int)f2bf(tile[8*lg+7][hh]) << 16);
            const u32x4 v = {w0, w1, w2, w3};
            *(u32x4*)(xT + ((size_t)b * H_ + h0 + hh) * LX + PADX + l0 + 8 * lg) = v;
        }
        if (l0 == 0) {                        // left pad [0, PADX) zeros
            #pragma unroll
            for (int it = 0; it < 8; ++it) {
                const int idx = j + 256 * it;           // 2048 vec-blocks
                const int row = idx >> 5, off = idx & 31;
                const u32x4 z = {};
                *(u32x4*)(xT + ((size_t)b * H_ + h0 + row) * LX + off * 8) = z;
            }
        }
    } else {
        const int h = bid - NXB;
        const float Dv = Dk[h];
        for (int l = (int)threadIdx.x; l < L_; l += 256) {
            const float a = kin[(size_t)h * L_ + l];
            float v = copysignf(fmaxf(fabsf(a) - 0.1f, 0.0f), a);
            if (l == 0) v += Dv;
            const unsigned short bv = f2bf(v);
            kR[(size_t)h * LK + (L_ - 1 - l)] = bv;                  // parity 0
            if (l <= L_ - 2)
                kR[((size_t)H_ + h) * LK + (L_ - 2 - l)] = bv;       // parity 1
        }
        if (threadIdx.x < 32) kR[(size_t)h * LK + L_ + threadIdx.x] = 0;
        if (threadIdx.x < 33) kR[((size_t)H_ + h) * LK + (L_ - 1) + threadIdx.x] = 0;
    }
}

// ---- main ----
__global__ __launch_bounds__(256, 2)
void longconv_main(const unsigned short* __restrict__ xT,
                   const unsigned short* __restrict__ kR,
                   unsigned int* __restrict__ outT)   // out_tmp packed bf16 pairs
{
    __shared__ __align__(16) unsigned char smem[SMEM_BYTES];
    unsigned short* xs = (unsigned short*)smem;
    unsigned short* ks = (unsigned short*)(smem + (size_t)XS_US * 2);
    float* oarea = (float*)(smem + (size_t)XS_US * 2 + (size_t)KS_US * 2);

    const int h   = blockIdx.x;
    const int tid = threadIdx.x;

    // stage in: x window (b-XOR swizzled 16B blocks) + k band (2 parity copies)
    constexpr int NXU = XS_BLKS * 4;          // 2160
    constexpr int NKU = 2 * (LK / 8);         // 1032
    for (int u = tid; u < NXU + NKU; u += 256) {
        if (u < NXU) {
            const int b = u / XS_BLKS, n = u - b * XS_BLKS;
            const u32x4 v = *(const u32x4*)(xT + ((size_t)b * H_ + h) * LX + 32 + n * 8);
            *(u32x4*)(xs + (size_t)b * XS_ROW + (size_t)(n ^ b) * 8) = v;
        } else {
            const int v2 = u - NXU;
            const int p = v2 / (LK / 8), i = v2 - p * (LK / 8);
            const u32x4 v = *(const u32x4*)(kR + ((size_t)p * H_ + h) * LK + i * 8);
            *(u32x4*)(ks + (size_t)p * LK + (size_t)i * 8) = v;
        }
    }
    __syncthreads();

    const int w  = tid >> 6, ln = tid & 63;
    const int m  = ln & 31,  q  = ln >> 5;
    const int t  = m >> 2,   b  = m & 3;
    const int si0 = w, si1 = 7 - w, si2 = 8 + w, si3 = 15 - w;  // ascending

    // A: frag(r)[j] = ks[p][(base-p) + r + j],  base = 3871 - m + 8q, p = base&1
    const int base = 3871 - m + 8 * q;
    const int p    = base & 1;
    const unsigned int* ap = (const unsigned int*)(ks + p * LK + (base - p));
    const unsigned short* xrow = xs + (size_t)b * XS_ROW;
    const int nb = 4 * t + q;

    auto Aload = [&](int r) -> s16x8 {
        const unsigned int* a = ap + (r >> 1);
        u32x4 aw; aw.x = a[0]; aw.y = a[1]; aw.z = a[2]; aw.w = a[3];
        return __builtin_bit_cast(s16x8, aw);
    };
    auto Bload = [&](int r, int si) -> s16x8 {
        const int nB = ((r + 256 * si) >> 3) + nb;
        return *(const s16x8*)(xrow + (size_t)((nB ^ b) * 8));
    };

    f32x16 acc0 = {}, acc1 = {}, acc2 = {}, acc3 = {};
    int r = 240;
    #pragma unroll 2
    for (; r >= -256 * si0; r -= 16) {
        const s16x8 af = Aload(r);
        acc0 = __builtin_amdgcn_mfma_f32_32x32x16_bf16(af, Bload(r, si0), acc0, 0, 0, 0);
        acc1 = __builtin_amdgcn_mfma_f32_32x32x16_bf16(af, Bload(r, si1), acc1, 0, 0, 0);
        acc2 = __builtin_amdgcn_mfma_f32_32x32x16_bf16(af, Bload(r, si2), acc2, 0, 0, 0);
        acc3 = __builtin_amdgcn_mfma_f32_32x32x16_bf16(af, Bload(r, si3), acc3, 0, 0, 0);
    }
    #pragma unroll 2
    for (; r >= -256 * si1; r -= 16) {
        const s16x8 af = Aload(r);
        acc1 = __builtin_amdgcn_mfma_f32_32x32x16_bf16(af, Bload(r, si1), acc1, 0, 0, 0);
        acc2 = __builtin_amdgcn_mfma_f32_32x32x16_bf16(af, Bload(r, si2), acc2, 0, 0, 0);
        acc3 = __builtin_amdgcn_mfma_f32_32x32x16_bf16(af, Bload(r, si3), acc3, 0, 0, 0);
    }
    #pragma unroll 2
    for (; r >= -256 * si2; r -= 16) {
        const s16x8 af = Aload(r);
        acc2 = __builtin_amdgcn_mfma_f32_32x32x16_bf16(af, Bload(r, si2), acc2, 0, 0, 0);
        acc3 = __builtin_amdgcn_mfma_f32_32x32x16_bf16(af, Bload(r, si3), acc3, 0, 0, 0);
    }
    #pragma unroll 2
    for (; r >= -256 * si3; r -= 16) {
        const s16x8 af = Aload(r);
        acc3 = __builtin_amdgcn_mfma_f32_32x32x16_bf16(af, Bload(r, si3), acc3, 0, 0, 0);
    }

    // ---- stage out via per-wave LDS area (t-rotation vs bank conflicts) ----
    float* ar = oarea + w * OAREA_DW;
    auto writeout = [&](const f32x16& acc, int si) {
        const int Ls = si * ST;
        #pragma unroll
        for (int rh = 0; rh < 2; ++rh) {
            #pragma unroll
            for (int rr2 = 0; rr2 < 2; ++rr2) {
                const int base4 = (8 * rr2 + 4 * q + 4 * t) & 15;
                f32x4 qd;
                qd.x = acc[4 * (2 * rh + rr2) + 0];
                qd.y = acc[4 * (2 * rh + rr2) + 1];
                qd.z = acc[4 * (2 * rh + rr2) + 2];
                qd.w = acc[4 * (2 * rh + rr2) + 3];
                *(f32x4*)(ar + b * 132 + 16 * t + base4) = qd;
            }
            __asm__ volatile("s_waitcnt lgkmcnt(0)" ::: "memory");
            #pragma unroll
            for (int bb = 0; bb < 4; ++bb) {
                const int g  = ln >> 3;
                const int uu = (2 * ln) & 15;
                const int s  = (uu + 4 * g) & 15;
                const float v0 = ar[bb * 132 + 16 * g + s];
                const float v1 = ar[bb * 132 + 16 * g + s + 1];
                const int l = 32 * g + 16 * rh + uu;
                const unsigned int pk =
                    (unsigned int)f2bf(v0) | ((unsigned int)f2bf(v1) << 16);
                outT[(((size_t)bb * H_ + h) * L_ + Ls + l) >> 1] = pk;
            }
            __asm__ volatile("s_waitcnt lgkmcnt(0)" ::: "memory");
        }
    };
    writeout(acc0, si0);
    writeout(acc1, si1);
    writeout(acc2, si2);
    writeout(acc3, si3);
}

// ---- out_tmp bf16 [B][H][L] -> out f32 [B][L][H], 16B/lane both sides ----
__global__ __launch_bounds__(256)
void untranspose(const unsigned short* __restrict__ outT, float* __restrict__ out)
{
    __shared__ float tile[64][65];
    const int bid = blockIdx.x;
    const int b  = bid / (nLt * nHt);
    const int r0 = bid % (nLt * nHt);
    const int l0 = (r0 / nHt) * 64;
    const int h0 = (r0 % nHt) * 64;
    const int j  = threadIdx.x;
    const int lg = j & 7;
    #pragma unroll
    for (int pp = 0; pp < 2; ++pp) {
        const int hh = (j >> 3) + 32 * pp;
        const u32x4 v = *(const u32x4*)(outT + ((size_t)b * H_ + h0 + hh) * L_ + l0 + 8 * lg);
        const unsigned short* pu = (const unsigned short*)&v;
        #pragma unroll
        for (int i = 0; i < 8; ++i) tile[8 * lg + i][hh] = bf2f(pu[i]);
    }
    __syncthreads();
    const int hg = j & 15;
    #pragma unroll
    for (int pp = 0; pp < 4; ++pp) {
        const int ll = (j >> 4) + 16 * pp;
        f32x4 v;
        v.x = tile[ll][4 * hg + 0];
        v.y = tile[ll][4 * hg + 1];
        v.z = tile[ll][4 * hg + 2];
        v.w = tile[ll][4 * hg + 3];
        *(f32x4*)(out + ((size_t)b * L_ + l0 + ll) * H_ + h0 + 4 * hg) = v;
    }
}

// ---- fallback: fp32 direct conv (only if ws too small) ----
constexpr int TLf = 32, Uf = 8, Wf = TLf + Uf - 1, HTf = 256;

__global__ __launch_bounds__(HTf)
void longconv_fp32(const float* __restrict__ x, const float* __restrict__ k,
                   const float* __restrict__ Dskip, float* __restrict__ out)
{
    const int h  = blockIdx.y * HTf + threadIdx.x;
    const int b  = blockIdx.z;
    const int lt = (int)gridDim.x - 1 - (int)blockIdx.x;
    const int L0 = lt * TLf;
    const float* __restrict__ xb = x + ((size_t)b * L_) * H_ + h;
    const float* __restrict__ kh = k + (size_t)h * L_;
    float acc[TLf]; float win[Wf];
    #pragma unroll
    for (int i = 0; i < Wf; ++i) {
        const int idx = L0 - (Uf - 1) + i;
        win[i] = (idx >= 0) ? xb[(size_t)idx * H_] : 0.0f;
    }
    const float Dv = Dskip[h];
    #pragma unroll
    for (int jj = 0; jj < TLf; ++jj) acc[jj] = win[jj + Uf - 1] * Dv;
    const int cmax = L0 / Uf + (TLf / Uf) - 1;
    for (int c = 0; c <= cmax; ++c) {
        float kr[Uf];
        #pragma unroll
        for (int u = 0; u < Uf; ++u) {
            const float a = kh[c * Uf + u];
            kr[u] = copysignf(fmaxf(fabsf(a) - 0.1f, 0.0f), a);
        }
        #pragma unroll
        for (int u = 0; u < Uf; ++u)
            #pragma unroll
            for (int jj = 0; jj < TLf; ++jj)
                acc[jj] = fmaf(kr[u], win[jj + (Uf - 1) - u], acc[jj]);
        if (c < cmax) {
            #pragma unroll
            for (int i = Wf - 1; i >= Uf; --i) win[i] = win[i - Uf];
            #pragma unroll
            for (int i = 0; i < Uf; ++i) {
                const int idx = L0 - (c + 1) * Uf - (Uf - 1) + i;
                win[i] = (idx >= 0) ? xb[(size_t)idx * H_] : 0.0f;
            }
        }
    }
    float* __restrict__ ob = out + ((size_t)b * L_ + L0) * H_ + h;
    #pragma unroll
    for (int jj = 0; jj < TLf; ++jj) ob[(size_t)jj * H_] = acc[jj];
}

extern "C" void kernel_launch(void* const* d_in, const int* in_sizes, int n_in,
                              void* d_out, int out_size, void* d_ws, size_t ws_size,
                              hipStream_t stream)
{
    const float* x  = (const float*)d_in[0];   // [B, L, H]
    const float* k  = (const float*)d_in[1];   // [1, H, L]
    const float* Dk = (const float*)d_in[2];   // [1, H]
    float* out = (float*)d_out;                // [B, L, H]

    if (ws_size >= WS_NEEDED) {
        unsigned short* xT = (unsigned short*)d_ws;
        unsigned short* kR = xT + XT_ELEMS;
        unsigned short* oT = kR + KR_ELEMS;
        prep<<<dim3(NXB + H_), dim3(256), 0, stream>>>(x, k, Dk, xT, kR);
        longconv_main<<<dim3(H_), dim3(256), 0, stream>>>(xT, kR, (unsigned int*)oT);
        untranspose<<<dim3(NXB), dim3(256), 0, stream>>>(oT, out);
    } else {
        dim3 grid(L_ / TLf, H_ / HTf, B_);
        longconv_fp32<<<grid, dim3(HTf), 0, stream>>>(x, k, Dk, out);
    }
}

// Round 5
// 215.104 us; speedup vs baseline: 9.2490x; 1.1134x over previous
//
#include <hip/hip_runtime.h>

// LongConvBlock, round 5: block-Toeplitz MFMA, LDS-staged, A-shared K-loop
// with fully affine (immediate-offset) LDS addressing.
// out[b,l,h] = sum_j x[b,j,h] * k'[h,l-j],  k'[0] += D[h].
//
// Main: block = one h (grid 1024), 4 waves; wave w owns si {w,7-w,8+w,15-w}
// with 4 accumulators. Bodies beta = 0..si3: body covers r in [-256beta,
// 240-256beta] ascending (16 chunks); si active iff si >= beta -> suffix
// phases, A-frag loaded once per chunk and fed to all active accumulators.
// B addresses: XOR swizzle splits into 2 affine tracks (iteration parity);
// all LDS offsets are immediates, bases bumped once per body.

typedef __attribute__((ext_vector_type(8)))  short s16x8;   // 8 bf16
typedef __attribute__((ext_vector_type(16))) float f32x16;  // 32x32 acc
typedef __attribute__((ext_vector_type(4)))  float f32x4;
typedef __attribute__((ext_vector_type(4)))  unsigned int u32x4;

constexpr int B_ = 4, L_ = 4096, H_ = 1024;
constexpr int PADX = 256;
constexpr int LX = L_ + PADX;    // 4352 xT row
constexpr int LK = L_ + 32;      // 4128 kR row
constexpr int ST = 256;          // outputs per (wave, si)
constexpr int NST = L_ / ST;     // 16

constexpr size_t XT_ELEMS = (size_t)B_ * H_ * LX;
constexpr size_t KR_ELEMS = (size_t)2 * H_ * LK;
constexpr size_t OT_ELEMS = (size_t)B_ * H_ * L_;
constexpr size_t WS_NEEDED = (XT_ELEMS + KR_ELEMS + OT_ELEMS) * sizeof(unsigned short);

constexpr int XS_ROW  = 4320;           // x window per b (l in [-224,4095])
constexpr int XS_BLKS = XS_ROW / 8;     // 540
constexpr int XS_US   = B_ * XS_ROW;    // 17280
constexpr int KS_US   = 2 * LK;         // 8256
constexpr int OAREA_DW = 4 * 132;       // 528 dwords per wave
constexpr int SMEM_BYTES = XS_US * 2 + KS_US * 2 + 4 * OAREA_DW * 4;  // 59520

constexpr int nHt = H_ / 64, nLt = L_ / 64;
constexpr int NXB = B_ * nLt * nHt;     // 4096 x-tile blocks in prep

__device__ __forceinline__ unsigned short f2bf(float f) {
    unsigned int u = __builtin_bit_cast(unsigned int, f);
    u += 0x7fffu + ((u >> 16) & 1u);    // RTNE
    return (unsigned short)(u >> 16);
}
__device__ __forceinline__ float bf2f(unsigned short u) {
    return __builtin_bit_cast(float, (unsigned int)u << 16);
}

// ---- prep (fused): x -> xT bf16 transposed (+left pad), k -> kR reversed ----
__global__ __launch_bounds__(256)
void prep(const float* __restrict__ x, const float* __restrict__ kin,
          const float* __restrict__ Dk,
          unsigned short* __restrict__ xT, unsigned short* __restrict__ kR)
{
    const int bid = blockIdx.x;
    if (bid < NXB) {
        __shared__ float tile[64][65];
        const int b  = bid / (nLt * nHt);
        const int r0 = bid % (nLt * nHt);
        const int l0 = (r0 / nHt) * 64;
        const int h0 = (r0 % nHt) * 64;
        const int j  = threadIdx.x;
        const int h4 = j & 15;            // h quad
        const int rg = j >> 4;            // row group
        #pragma unroll
        for (int it = 0; it < 4; ++it) {
            const int lr = rg + 16 * it;
            const f32x4 v = *(const f32x4*)(x + ((size_t)b * L_ + l0 + lr) * H_ + h0 + 4 * h4);
            tile[lr][4 * h4 + 0] = v.x; tile[lr][4 * h4 + 1] = v.y;
            tile[lr][4 * h4 + 2] = v.z; tile[lr][4 * h4 + 3] = v.w;
        }
        __syncthreads();
        const int lg = j & 7;             // 8-element l group
        #pragma unroll
        for (int pp = 0; pp < 2; ++pp) {
            const int hh = (j >> 3) + 32 * pp;
            unsigned int w0 = (unsigned int)f2bf(tile[8*lg+0][hh]) | ((unsigned int)f2bf(tile[8*lg+1][hh]) << 16);
            unsigned int w1 = (unsigned int)f2bf(tile[8*lg+2][hh]) | ((unsigned int)f2bf(tile[8*lg+3][hh]) << 16);
            unsigned int w2 = (unsigned int)f2bf(tile[8*lg+4][hh]) | ((unsigned int)f2bf(tile[8*lg+5][hh]) << 16);
            unsigned int w3 = (unsigned int)f2bf(tile[8*lg+6][hh]) | ((unsigned int)f2bf(tile[8*lg+7][hh]) << 16);
            const u32x4 v = {w0, w1, w2, w3};
            *(u32x4*)(xT + ((size_t)b * H_ + h0 + hh) * LX + PADX + l0 + 8 * lg) = v;
        }
        if (l0 == 0) {                    // left pad [0, PADX) zeros
            #pragma unroll
            for (int it = 0; it < 8; ++it) {
                const int idx = j + 256 * it;         // 2048 vec-blocks
                const int row = idx >> 5, off = idx & 31;
                const u32x4 z = {};
                *(u32x4*)(xT + ((size_t)b * H_ + h0 + row) * LX + off * 8) = z;
            }
        }
    } else {
        const int h = bid - NXB;
        const float Dv = Dk[h];
        for (int l = (int)threadIdx.x; l < L_; l += 256) {
            const float a = kin[(size_t)h * L_ + l];
            float v = copysignf(fmaxf(fabsf(a) - 0.1f, 0.0f), a);
            if (l == 0) v += Dv;
            const unsigned short bv = f2bf(v);
            kR[(size_t)h * LK + (L_ - 1 - l)] = bv;                  // parity 0
            if (l <= L_ - 2)
                kR[((size_t)H_ + h) * LK + (L_ - 2 - l)] = bv;       // parity 1
        }
        if (threadIdx.x < 32) kR[(size_t)h * LK + L_ + threadIdx.x] = 0;
        if (threadIdx.x < 33) kR[((size_t)H_ + h) * LK + (L_ - 1) + threadIdx.x] = 0;
    }
}

// One 16-chunk body: shared A-frag -> up to 4 MFMAs; all offsets immediate.
#define BODY(DO0, DO1, DO2, DO3)                                            \
  {                                                                         \
    _Pragma("unroll")                                                       \
    for (int i = 0; i < 16; ++i) {                                          \
      u32x4 aw;                                                             \
      aw.x = abase[8*i+0]; aw.y = abase[8*i+1];                             \
      aw.z = abase[8*i+2]; aw.w = abase[8*i+3];                             \
      const s16x8 af = __builtin_bit_cast(s16x8, aw);                       \
      const int io = 32 * (i >> 1);                                         \
      if (DO3) acc3 = __builtin_amdgcn_mfma_f32_32x32x16_bf16(              \
            af, *(const s16x8*)(((i & 1) ? t3b : t3a) + io), acc3, 0,0,0);  \
      if (DO2) acc2 = __builtin_amdgcn_mfma_f32_32x32x16_bf16(              \
            af, *(const s16x8*)(((i & 1) ? t2b : t2a) + io), acc2, 0,0,0);  \
      if (DO1) acc1 = __builtin_amdgcn_mfma_f32_32x32x16_bf16(              \
            af, *(const s16x8*)(((i & 1) ? t1b : t1a) + io), acc1, 0,0,0);  \
      if (DO0) acc0 = __builtin_amdgcn_mfma_f32_32x32x16_bf16(              \
            af, *(const s16x8*)(((i & 1) ? t0b : t0a) + io), acc0, 0,0,0);  \
    }                                                                       \
    abase -= 128;                                                           \
    if (DO3) { t3a -= 256; t3b -= 256; }                                    \
    if (DO2) { t2a -= 256; t2b -= 256; }                                    \
    if (DO1) { t1a -= 256; t1b -= 256; }                                    \
    if (DO0) { t0a -= 256; t0b -= 256; }                                    \
  }

// ---- main ----
__global__ __launch_bounds__(256, 2)
void longconv_main(const unsigned short* __restrict__ xT,
                   const unsigned short* __restrict__ kR,
                   unsigned int* __restrict__ outT)   // out_tmp packed bf16 pairs
{
    __shared__ __align__(16) unsigned char smem[SMEM_BYTES];
    unsigned short* xs = (unsigned short*)smem;
    unsigned short* ks = (unsigned short*)(smem + (size_t)XS_US * 2);
    float* oarea = (float*)(smem + (size_t)XS_US * 2 + (size_t)KS_US * 2);

    const int h   = blockIdx.x;
    const int tid = threadIdx.x;

    // stage in: x window (b-XOR swizzled 16B blocks) + k band (2 parity copies)
    constexpr int NXU = XS_BLKS * 4;          // 2160
    constexpr int NKU = 2 * (LK / 8);         // 1032
    for (int u = tid; u < NXU + NKU; u += 256) {
        if (u < NXU) {
            const int b = u / XS_BLKS, n = u - b * XS_BLKS;
            const u32x4 v = *(const u32x4*)(xT + ((size_t)b * H_ + h) * LX + 32 + n * 8);
            *(u32x4*)(xs + (size_t)b * XS_ROW + (size_t)(n ^ b) * 8) = v;
        } else {
            const int v2 = u - NXU;
            const int p = v2 / (LK / 8), i = v2 - p * (LK / 8);
            const u32x4 v = *(const u32x4*)(kR + ((size_t)p * H_ + h) * LK + i * 8);
            *(u32x4*)(ks + (size_t)p * LK + (size_t)i * 8) = v;
        }
    }
    __syncthreads();

    const int w  = tid >> 6, ln = tid & 63;
    const int m  = ln & 31,  q  = ln >> 5;
    const int t  = m >> 2,   b  = m & 3;
    const int si0 = w, si1 = 7 - w, si2 = 8 + w, si3 = 15 - w;  // ascending

    // A: frag(r)[j] = ks[p][(base-p) + r + j],  base = 3871 - m + 8q, p = base&1
    const int base = 3871 - m + 8 * q;
    const int p    = base & 1;
    const unsigned int* abase = (const unsigned int*)(ks + p * LK + (base - p));
    const unsigned short* xrow = xs + (size_t)b * XS_ROW;
    const int nb = 4 * t + q;

    // B tracks: body beta, chunk i: n = 32*(si-beta) + nb + 2i; even/odd i
    // tracks step +4 blocks (XOR-affine: +4 preserves low 2 bits).
    auto mk = [&](int si, int par) -> const unsigned short* {
        const int n = 32 * si + nb + 2 * par;
        return xrow + (size_t)((n ^ b) * 8);
    };
    const unsigned short *t0a = mk(si0, 0), *t0b = mk(si0, 1);
    const unsigned short *t1a = mk(si1, 0), *t1b = mk(si1, 1);
    const unsigned short *t2a = mk(si2, 0), *t2b = mk(si2, 1);
    const unsigned short *t3a = mk(si3, 0), *t3b = mk(si3, 1);

    f32x16 acc0 = {}, acc1 = {}, acc2 = {}, acc3 = {};
    int beta = 0;
    for (; beta <= si0; ++beta) BODY(1, 1, 1, 1);
    for (; beta <= si1; ++beta) BODY(0, 1, 1, 1);
    for (; beta <= si2; ++beta) BODY(0, 0, 1, 1);
    for (; beta <= si3; ++beta) BODY(0, 0, 0, 1);

    // ---- stage out via per-wave LDS area (t-rotation vs bank conflicts) ----
    float* ar = oarea + w * OAREA_DW;
    auto writeout = [&](const f32x16& acc, int si) {
        const int Ls = si * ST;
        #pragma unroll
        for (int rh = 0; rh < 2; ++rh) {
            #pragma unroll
            for (int rr2 = 0; rr2 < 2; ++rr2) {
                const int base4 = (8 * rr2 + 4 * q + 4 * t) & 15;
                f32x4 qd;
                qd.x = acc[4 * (2 * rh + rr2) + 0];
                qd.y = acc[4 * (2 * rh + rr2) + 1];
                qd.z = acc[4 * (2 * rh + rr2) + 2];
                qd.w = acc[4 * (2 * rh + rr2) + 3];
                *(f32x4*)(ar + b * 132 + 16 * t + base4) = qd;
            }
            __asm__ volatile("s_waitcnt lgkmcnt(0)" ::: "memory");
            #pragma unroll
            for (int bb = 0; bb < 4; ++bb) {
                const int g  = ln >> 3;
                const int uu = (2 * ln) & 15;
                const int s  = (uu + 4 * g) & 15;
                const float v0 = ar[bb * 132 + 16 * g + s];
                const float v1 = ar[bb * 132 + 16 * g + s + 1];
                const int l = 32 * g + 16 * rh + uu;
                const unsigned int pk =
                    (unsigned int)f2bf(v0) | ((unsigned int)f2bf(v1) << 16);
                outT[(((size_t)bb * H_ + h) * L_ + Ls + l) >> 1] = pk;
            }
            __asm__ volatile("s_waitcnt lgkmcnt(0)" ::: "memory");
        }
    };
    writeout(acc0, si0);
    writeout(acc1, si1);
    writeout(acc2, si2);
    writeout(acc3, si3);
}

// ---- out_tmp bf16 [B][H][L] -> out f32 [B][L][H], 16B/lane both sides ----
__global__ __launch_bounds__(256)
void untranspose(const unsigned short* __restrict__ outT, float* __restrict__ out)
{
    __shared__ float tile[64][65];
    const int bid = blockIdx.x;
    const int b  = bid / (nLt * nHt);
    const int r0 = bid % (nLt * nHt);
    const int l0 = (r0 / nHt) * 64;
    const int h0 = (r0 % nHt) * 64;
    const int j  = threadIdx.x;
    const int lg = j & 7;
    #pragma unroll
    for (int pp = 0; pp < 2; ++pp) {
        const int hh = (j >> 3) + 32 * pp;
        const u32x4 v = *(const u32x4*)(outT + ((size_t)b * H_ + h0 + hh) * L_ + l0 + 8 * lg);
        const unsigned short* pu = (const unsigned short*)&v;
        #pragma unroll
        for (int i = 0; i < 8; ++i) tile[8 * lg + i][hh] = bf2f(pu[i]);
    }
    __syncthreads();
    const int hg = j & 15;
    #pragma unroll
    for (int pp = 0; pp < 4; ++pp) {
        const int ll = (j >> 4) + 16 * pp;
        f32x4 v;
        v.x = tile[ll][4 * hg + 0];
        v.y = tile[ll][4 * hg + 1];
        v.z = tile[ll][4 * hg + 2];
        v.w = tile[ll][4 * hg + 3];
        *(f32x4*)(out + ((size_t)b * L_ + l0 + ll) * H_ + h0 + 4 * hg) = v;
    }
}

// ---- fallback: fp32 direct conv (only if ws too small) ----
constexpr int TLf = 32, Uf = 8, Wf = TLf + Uf - 1, HTf = 256;

__global__ __launch_bounds__(HTf)
void longconv_fp32(const float* __restrict__ x, const float* __restrict__ k,
                   const float* __restrict__ Dskip, float* __restrict__ out)
{
    const int h  = blockIdx.y * HTf + threadIdx.x;
    const int b  = blockIdx.z;
    const int lt = (int)gridDim.x - 1 - (int)blockIdx.x;
    const int L0 = lt * TLf;
    const float* __restrict__ xb = x + ((size_t)b * L_) * H_ + h;
    const float* __restrict__ kh = k + (size_t)h * L_;
    float acc[TLf]; float win[Wf];
    #pragma unroll
    for (int i = 0; i < Wf; ++i) {
        const int idx = L0 - (Uf - 1) + i;
        win[i] = (idx >= 0) ? xb[(size_t)idx * H_] : 0.0f;
    }
    const float Dv = Dskip[h];
    #pragma unroll
    for (int jj = 0; jj < TLf; ++jj) acc[jj] = win[jj + Uf - 1] * Dv;
    const int cmax = L0 / Uf + (TLf / Uf) - 1;
    for (int c = 0; c <= cmax; ++c) {
        float kr[Uf];
        #pragma unroll
        for (int u = 0; u < Uf; ++u) {
            const float a = kh[c * Uf + u];
            kr[u] = copysignf(fmaxf(fabsf(a) - 0.1f, 0.0f), a);
        }
        #pragma unroll
        for (int u = 0; u < Uf; ++u)
            #pragma unroll
            for (int jj = 0; jj < TLf; ++jj)
                acc[jj] = fmaf(kr[u], win[jj + (Uf - 1) - u], acc[jj]);
        if (c < cmax) {
            #pragma unroll
            for (int i = Wf - 1; i >= Uf; --i) win[i] = win[i - Uf];
            #pragma unroll
            for (int i = 0; i < Uf; ++i) {
                const int idx = L0 - (c + 1) * Uf - (Uf - 1) + i;
                win[i] = (idx >= 0) ? xb[(size_t)idx * H_] : 0.0f;
            }
        }
    }
    float* __restrict__ ob = out + ((size_t)b * L_ + L0) * H_ + h;
    #pragma unroll
    for (int jj = 0; jj < TLf; ++jj) ob[(size_t)jj * H_] = acc[jj];
}

extern "C" void kernel_launch(void* const* d_in, const int* in_sizes, int n_in,
                              void* d_out, int out_size, void* d_ws, size_t ws_size,
                              hipStream_t stream)
{
    const float* x  = (const float*)d_in[0];   // [B, L, H]
    const float* k  = (const float*)d_in[1];   // [1, H, L]
    const float* Dk = (const float*)d_in[2];   // [1, H]
    float* out = (float*)d_out;                // [B, L, H]

    if (ws_size >= WS_NEEDED) {
        unsigned short* xT = (unsigned short*)d_ws;
        unsigned short* kR = xT + XT_ELEMS;
        unsigned short* oT = kR + KR_ELEMS;
        prep<<<dim3(NXB + H_), dim3(256), 0, stream>>>(x, k, Dk, xT, kR);
        longconv_main<<<dim3(H_), dim3(256), 0, stream>>>(xT, kR, (unsigned int*)oT);
        untranspose<<<dim3(NXB), dim3(256), 0, stream>>>(oT, out);
    } else {
        dim3 grid(L_ / TLf, H_ / HTf, B_);
        longconv_fp32<<<grid, dim3(HTf), 0, stream>>>(x, k, Dk, out);
    }
}